// Round 3
// 703.559 us; speedup vs baseline: 1.0751x; 1.0751x over previous
//
#include <hip/hip_runtime.h>
#include <cstdint>
#include <cstddef>

typedef unsigned short u16;
typedef __attribute__((ext_vector_type(8))) short bf16x8;
typedef __attribute__((ext_vector_type(4))) float f32x4;

__device__ __forceinline__ u16 f2bf(float f) {
    unsigned u = __float_as_uint(f);
    u += 0x7FFF + ((u >> 16) & 1);   // RNE
    return (u16)(u >> 16);
}
__device__ __forceinline__ float bf2f(u16 b) {
    return __uint_as_float(((unsigned)b) << 16);
}

// ---------------- fp32 -> bf16 conversion (4 elems/thread) ----------------
__global__ __launch_bounds__(256) void cvt_bf16(const float4* __restrict__ in,
                                                u16* __restrict__ out, int n4) {
    int i = blockIdx.x * 256 + threadIdx.x;
    if (i >= n4) return;
    float4 v = in[i];
    ushort4 o;
    o.x = f2bf(v.x); o.y = f2bf(v.y); o.z = f2bf(v.z); o.w = f2bf(v.w);
    ((ushort4*)out)[i] = o;
}

__device__ __forceinline__ void gl_lds16(const u16* g, u16* l) {
    __builtin_amdgcn_global_load_lds(
        (const __attribute__((address_space(1))) void*)g,
        (__attribute__((address_space(3))) void*)l, 16, 0, 0);
}

// =====================================================================
// 256x256 8-phase bf16 GEMM:  C[M,N] = A[M,K] * Bt[N,K]^T
// BK=64, 8 waves (2Mx4N), per-wave 128x64 output (8x4 frags 16x16x32).
// LDS 128 KiB: 2 dbuf x (A 32KB + B 32KB). Chunk-XOR swizzle: row r's
// 16B chunk c stored at c ^ (r&7); applied via pre-swizzled GLOBAL src
// (global_load_lds dest is WAVE-UNIFORM base; HW adds lane*16 -> linear).
// Per K-tile: 4 phases x 16 MFMA; reads confined to P1 (ks0) + P2 (ks1);
// stages: P1:(g+1).Ah1  P2:(g+1).Bh1  P3:(g+2).Ah0  P4:(g+2).Bh0.
// vmcnt(4) at group end (keeps P3/P4 stages in flight); vmcnt(0) at tail.
// Hazard proof: all reads of tile g retire (lgkmcnt(0)) before P2's
// closing barrier; P3/P4 stages into the same buffer issue only after
// that barrier. At P4's vmcnt(4) the 4 newest outstanding VMEM ops are
// exactly (g+2).Ah0/Bh0, so every stage of tile g+1 has landed before
// iteration g+1 reads it.
// =====================================================================
#define MFMA16(a, b, c) __builtin_amdgcn_mfma_f32_16x16x32_bf16(a, b, c, 0, 0, 0)

__device__ __forceinline__ void BARRIER() {
    asm volatile("" ::: "memory");
    __builtin_amdgcn_s_barrier();
    asm volatile("" ::: "memory");
}
#define LGKM0() asm volatile("s_waitcnt lgkmcnt(0)" ::: "memory")

__device__ __forceinline__ bf16x8 lds_frag(const u16* base, int r, int c) {
    return *(const bf16x8*)((const char*)base + (r << 7) + ((c ^ (r & 7)) << 4));
}

// gbase includes tile-row origin and the per-lane swizzled chunk offset.
// lbase+wuoff is WAVE-UNIFORM; hardware writes lane l's 16B at +l*16,
// which lands row (w*8 + l>>3), slot (l&7) of the [row][slot] layout --
// matching the pre-swizzled global source chunk ((l&7) ^ (l>>3)).
__device__ __forceinline__ void stage_half(const u16* gbase, int K, u16* lbase,
                                           int kt, int h, int srow, int wuoff)
{
    const u16* gp = gbase + (size_t)(h * 128 + srow) * K + kt * 64;
    char* lp = (char*)lbase + h * 16384 + wuoff;          // wave-uniform
    gl_lds16(gp, (u16*)lp);                               // rows h*128 + [0,64)
    gl_lds16(gp + (size_t)64 * K, (u16*)(lp + 8192));     // rows h*128 + [64,128)
}

template <bool IS_QKV>
__global__ __launch_bounds__(512, 2)
void gemm256(const u16* __restrict__ A, const u16* __restrict__ Bt,
             const float* __restrict__ bias, void* __restrict__ Cout,
             int M, int N, int K)
{
    __shared__ u16 As[2][16384];   // [buf][256 rows x 64 cols]
    __shared__ u16 Bs[2][16384];

    const int tid = threadIdx.x;
    const int w   = tid >> 6;
    const int l   = tid & 63;
    const int wr  = w >> 2;            // 0..1  (M half)
    const int wc  = w & 3;             // 0..3  (N quarter)
    const int fr  = l & 15;            // fragment row
    const int ck0 = l >> 4;            // k-chunk 0..3 (ks0); ks1 = ck0+4

    // ---- bijective XCD-aware block remap (m204) ----
    const int gx = gridDim.x;
    const int nwg = gx * gridDim.y;
    const int orig = blockIdx.y * gx + blockIdx.x;
    const int qq = nwg >> 3, rr = nwg & 7;
    const int xcd = orig & 7, idx = orig >> 3;
    const int wg = (xcd < rr) ? (xcd * (qq + 1) + idx)
                              : (rr * (qq + 1) + (xcd - rr) * qq + idx);
    const int bx = wg % gx, by = wg / gx;
    const int m0 = by * 256, n0 = bx * 256;

    // ---- staging coords: this lane sources row srow(+64), swizzled chunk ----
    const int srow   = w * 8 + (l >> 3);            // 0..63
    const int schunk = ((l & 7) ^ (l >> 3)) * 8;    // element offset of 16B chunk
    const int wuoff  = w * 1024;                    // bytes, wave-uniform LDS base

    const u16* Ag = A  + (size_t)m0 * K + schunk;
    const u16* Bg = Bt + (size_t)n0 * K + schunk;

    f32x4 acc[8][4] = {};
    const int NT = K >> 6;             // K-tiles of 64 (=12 here)

    // ---- prologue: tile0 fully, tile1 h0 ----
    stage_half(Ag, K, As[0], 0, 0, srow, wuoff);
    stage_half(Bg, K, Bs[0], 0, 0, srow, wuoff);
    stage_half(Ag, K, As[0], 0, 1, srow, wuoff);
    stage_half(Bg, K, Bs[0], 0, 1, srow, wuoff);
    stage_half(Ag, K, As[1], 1, 0, srow, wuoff);
    stage_half(Bg, K, Bs[1], 1, 0, srow, wuoff);
    asm volatile("s_waitcnt vmcnt(4)" ::: "memory");   // tile0 done; tile1.h0 in flight
    BARRIER();

    for (int g = 0; g < NT; ++g) {
        const u16* Ab = As[g & 1];
        const u16* Bb = Bs[g & 1];
        u16* Anx = As[(g + 1) & 1];
        u16* Bnx = Bs[(g + 1) & 1];
        u16* Acu = As[g & 1];
        u16* Bcu = Bs[g & 1];

        bf16x8 a0[8], a1[8], b0[4], b1[4];

        // ---------- P1: read ks0 (a0, b0[0..1]), stage (g+1).Ah1, MFMA ks0 x n0-1 ----------
        #pragma unroll
        for (int mi = 0; mi < 8; ++mi) a0[mi] = lds_frag(Ab, wr * 128 + mi * 16 + fr, ck0);
        b0[0] = lds_frag(Bb, wc * 64 + 0 * 16 + fr, ck0);
        b0[1] = lds_frag(Bb, wc * 64 + 1 * 16 + fr, ck0);
        if (g + 1 < NT) stage_half(Ag, K, Anx, g + 1, 1, srow, wuoff);
        BARRIER();
        LGKM0();
        __builtin_amdgcn_s_setprio(1);
        #pragma unroll
        for (int mi = 0; mi < 8; ++mi) {
            acc[mi][0] = MFMA16(a0[mi], b0[0], acc[mi][0]);
            acc[mi][1] = MFMA16(a0[mi], b0[1], acc[mi][1]);
        }
        __builtin_amdgcn_s_setprio(0);
        BARRIER();

        // ---------- P2: read b0[2..3] + ks1 (a1, b1), stage (g+1).Bh1, MFMA ks0 x n2-3 ----------
        b0[2] = lds_frag(Bb, wc * 64 + 2 * 16 + fr, ck0);
        b0[3] = lds_frag(Bb, wc * 64 + 3 * 16 + fr, ck0);
        #pragma unroll
        for (int mi = 0; mi < 8; ++mi) a1[mi] = lds_frag(Ab, wr * 128 + mi * 16 + fr, ck0 + 4);
        #pragma unroll
        for (int ni = 0; ni < 4; ++ni) b1[ni] = lds_frag(Bb, wc * 64 + ni * 16 + fr, ck0 + 4);
        if (g + 1 < NT) stage_half(Bg, K, Bnx, g + 1, 1, srow, wuoff);
        BARRIER();
        LGKM0();   // all reads of this buffer retired before P3's stages
        __builtin_amdgcn_s_setprio(1);
        #pragma unroll
        for (int mi = 0; mi < 8; ++mi) {
            acc[mi][2] = MFMA16(a0[mi], b0[2], acc[mi][2]);
            acc[mi][3] = MFMA16(a0[mi], b0[3], acc[mi][3]);
        }
        __builtin_amdgcn_s_setprio(0);
        BARRIER();

        // ---------- P3: stage (g+2).Ah0, MFMA ks1 x n0-1 ----------
        if (g + 2 < NT) stage_half(Ag, K, Acu, g + 2, 0, srow, wuoff);
        BARRIER();
        __builtin_amdgcn_s_setprio(1);
        #pragma unroll
        for (int mi = 0; mi < 8; ++mi) {
            acc[mi][0] = MFMA16(a1[mi], b1[0], acc[mi][0]);
            acc[mi][1] = MFMA16(a1[mi], b1[1], acc[mi][1]);
        }
        __builtin_amdgcn_s_setprio(0);
        BARRIER();

        // ---------- P4: stage (g+2).Bh0, MFMA ks1 x n2-3, counted vmcnt ----------
        if (g + 2 < NT) stage_half(Bg, K, Bcu, g + 2, 0, srow, wuoff);
        __builtin_amdgcn_s_setprio(1);
        #pragma unroll
        for (int mi = 0; mi < 8; ++mi) {
            acc[mi][2] = MFMA16(a1[mi], b1[2], acc[mi][2]);
            acc[mi][3] = MFMA16(a1[mi], b1[3], acc[mi][3]);
        }
        __builtin_amdgcn_s_setprio(0);
        if (g < NT - 2) { asm volatile("s_waitcnt vmcnt(4)" ::: "memory"); }
        else            { asm volatile("s_waitcnt vmcnt(0)" ::: "memory"); }
        BARRIER();
    }

    // ---- epilogue: C/D layout col = lane&15, row = (lane>>4)*4 + reg ----
    if (IS_QKV) {
        u16* C = (u16*)Cout;
        #pragma unroll
        for (int mi = 0; mi < 8; ++mi) {
            const int r0 = m0 + wr * 128 + mi * 16 + (l >> 4) * 4;
            #pragma unroll
            for (int ni = 0; ni < 4; ++ni) {
                const int col = n0 + wc * 64 + ni * 16 + fr;
                const float sc = (col < 768) ? 0.125f : 1.0f;   // q * HD^-0.5
                #pragma unroll
                for (int r = 0; r < 4; ++r)
                    C[(size_t)(r0 + r) * N + col] = f2bf(acc[mi][ni][r] * sc);
            }
        }
    } else {
        float* C = (float*)Cout;
        #pragma unroll
        for (int mi = 0; mi < 8; ++mi) {
            const int r0 = m0 + wr * 128 + mi * 16 + (l >> 4) * 4;
            #pragma unroll
            for (int ni = 0; ni < 4; ++ni) {
                const int col = n0 + wc * 64 + ni * 16 + fr;
                const float b = bias[col];
                #pragma unroll
                for (int r = 0; r < 4; ++r)
                    C[(size_t)(r0 + r) * N + col] = acc[mi][ni][r] + b;
            }
        }
    }
}

// ---------------- sparse 3x3-window attention (v2) ----------------
// 8 lanes per query, 8 dims per lane, 8 queries per wave.
// qkv layout [B*N][3*768] bf16, q pre-scaled by 0.125. out [B*N][768] bf16.
__device__ __forceinline__ void load_bf8(const u16* p, float* f) {
    uint4 d = *(const uint4*)p;
    f[0] = __uint_as_float(d.x << 16); f[1] = __uint_as_float(d.x & 0xFFFF0000u);
    f[2] = __uint_as_float(d.y << 16); f[3] = __uint_as_float(d.y & 0xFFFF0000u);
    f[4] = __uint_as_float(d.z << 16); f[5] = __uint_as_float(d.z & 0xFFFF0000u);
    f[6] = __uint_as_float(d.w << 16); f[7] = __uint_as_float(d.w & 0xFFFF0000u);
}

__global__ __launch_bounds__(256)
void attn_sparse2(const u16* __restrict__ qkv, const float* __restrict__ rpb,
                  u16* __restrict__ out)
{
    const int lane = threadIdx.x & 63;
    const int wid  = blockIdx.x * 4 + (threadIdx.x >> 6);
    const int sub  = lane >> 3;          // query within wave (0..7)
    const int sl   = lane & 7;           // dims [sl*8, sl*8+8)
    const int gq   = wid * 8 + sub;      // 0 .. 602111  (= bt*12 + h)
    const int bt   = gq / 12;
    const int h    = gq - bt * 12;
    const int t    = bt % 196;
    const int i    = t / 14, j = t % 14;

    const size_t rowbase = (size_t)(bt - t) * 2304 + h * 64 + sl * 8;

    float qf[8];
    load_bf8(qkv + (size_t)bt * 2304 + h * 64 + sl * 8, qf);

    // pass 1: scores
    float s[9];
    int   t2a[9];
    #pragma unroll
    for (int di = -1; di <= 1; ++di) {
        #pragma unroll
        for (int dj = -1; dj <= 1; ++dj) {
            const int idx = (di + 1) * 3 + (dj + 1);
            const int i2 = i + di, j2 = j + dj;
            const bool valid = ((unsigned)i2 < 14u) && ((unsigned)j2 < 14u);
            const int t2 = valid ? (i2 * 14 + j2) : t;
            t2a[idx] = t2;
            float kf[8];
            load_bf8(qkv + rowbase + (size_t)t2 * 2304 + 768, kf);
            float p = qf[0] * kf[0];
            #pragma unroll
            for (int d = 1; d < 8; ++d) p = fmaf(qf[d], kf[d], p);
            p += __shfl_xor(p, 1);
            p += __shfl_xor(p, 2);
            p += __shfl_xor(p, 4);
            const int ridx = (13 - di) * 27 + (13 - dj);
            s[idx] = valid ? (p + rpb[ridx * 12 + h]) : -1e30f;
        }
    }
    float mx = s[0];
    #pragma unroll
    for (int a = 1; a < 9; ++a) mx = fmaxf(mx, s[a]);

    // pass 2: softmax + weighted V
    float den = 0.f, o[8] = {};
    #pragma unroll
    for (int a = 0; a < 9; ++a) {
        float vf[8];
        load_bf8(qkv + rowbase + (size_t)t2a[a] * 2304 + 1536, vf);
        const float p = __expf(s[a] - mx);   // invalid -> exp(-huge) = 0
        den += p;
        #pragma unroll
        for (int d = 0; d < 8; ++d) o[d] = fmaf(p, vf[d], o[d]);
    }
    const float r = 1.0f / den;
    ushort4 o0, o1;
    o0.x = f2bf(o[0] * r); o0.y = f2bf(o[1] * r);
    o0.z = f2bf(o[2] * r); o0.w = f2bf(o[3] * r);
    o1.x = f2bf(o[4] * r); o1.y = f2bf(o[5] * r);
    o1.z = f2bf(o[6] * r); o1.w = f2bf(o[7] * r);
    u16* op = out + (size_t)bt * 768 + h * 64 + sl * 8;
    *(ushort4*)op = o0;
    *(ushort4*)(op + 4) = o1;
}

// ---------------- launch ----------------
extern "C" void kernel_launch(void* const* d_in, const int* in_sizes, int n_in,
                              void* d_out, int out_size, void* d_ws, size_t ws_size,
                              hipStream_t stream)
{
    const float* x      = (const float*)d_in[0];   // [256,196,768]
    const float* w_qkv  = (const float*)d_in[1];   // [2304,768]
    const float* rpb    = (const float*)d_in[2];   // [729,12]
    const float* proj_w = (const float*)d_in[3];   // [768,768]
    const float* proj_b = (const float*)d_in[4];   // [768]
    // d_in[5] mask, d_in[6] rel_idx: handled analytically
    float* out = (float*)d_out;                    // [256,196,768]

    char* ws = (char*)d_ws;
    u16* x_bf    = (u16*)(ws);                    // 50176*768*2  = 77,070,336 B
    u16* wqkv_bf = (u16*)(ws + 77070336ULL);      // 2304*768*2   =  3,538,944 B
    u16* pw_bf   = (u16*)(ws + 80609280ULL);      // 768*768*2    =  1,179,648 B
    u16* qkv_bf  = (u16*)(ws + 81788928ULL);      // 50176*2304*2 = 231,211,008 B
    u16* attn_bf = (u16*)(ws + 312999936ULL);     // 50176*768*2  = 77,070,336 B
    // total 390,070,272 B

    cvt_bf16<<<37632, 256, 0, stream>>>((const float4*)x,      x_bf,    9633792);
    cvt_bf16<<<1728,  256, 0, stream>>>((const float4*)w_qkv,  wqkv_bf, 442368);
    cvt_bf16<<<576,   256, 0, stream>>>((const float4*)proj_w, pw_bf,   147456);

    // qkv = x @ w_qkv^T  (M=50176, N=2304, K=768), q cols scaled by 0.125
    gemm256<true><<<dim3(9, 196), 512, 0, stream>>>(
        x_bf, wqkv_bf, nullptr, qkv_bf, 50176, 2304, 768);

    // sparse local attention: 602112 queries, 8 per wave, 4 waves per block
    attn_sparse2<<<18816, 256, 0, stream>>>(qkv_bf, rpb, attn_bf);

    // out = attn @ proj_w^T + proj_b  (M=50176, N=768, K=768), fp32 out
    gemm256<false><<<dim3(3, 196), 512, 0, stream>>>(
        attn_bf, pw_bf, proj_b, out, 50176, 768, 768);
}

// Round 4
// 686.921 us; speedup vs baseline: 1.1012x; 1.0242x over previous
//
#include <hip/hip_runtime.h>
#include <cstdint>
#include <cstddef>

typedef unsigned short u16;
typedef __attribute__((ext_vector_type(8))) short bf16x8;
typedef __attribute__((ext_vector_type(4))) float f32x4;

__device__ __forceinline__ u16 f2bf(float f) {
    unsigned u = __float_as_uint(f);
    u += 0x7FFF + ((u >> 16) & 1);   // RNE
    return (u16)(u >> 16);
}

// ---------------- fp32 -> bf16 conversion (4 elems/thread) ----------------
__global__ __launch_bounds__(256) void cvt_bf16(const float4* __restrict__ in,
                                                u16* __restrict__ out, int n4) {
    int i = blockIdx.x * 256 + threadIdx.x;
    if (i >= n4) return;
    float4 v = in[i];
    ushort4 o;
    o.x = f2bf(v.x); o.y = f2bf(v.y); o.z = f2bf(v.z); o.w = f2bf(v.w);
    ((ushort4*)out)[i] = o;
}

__device__ __forceinline__ void gl_lds16(const u16* g, u16* l) {
    __builtin_amdgcn_global_load_lds(
        (const __attribute__((address_space(1))) void*)g,
        (__attribute__((address_space(3))) void*)l, 16, 0, 0);
}

// =====================================================================
// 256x256 8-phase bf16 GEMM:  C[M,N] = A[M,K] * Bt[N,K]^T
// BK=64, 8 waves (2Mx4N), per-wave 128x64 output (8x4 frags 16x16x32).
// LDS 128 KiB: 2 dbuf x (A 32KB + B 32KB). Chunk-XOR swizzle: row r's
// 16B chunk c stored at c ^ (r&7); applied via pre-swizzled GLOBAL src
// (global_load_lds dest is WAVE-UNIFORM base; HW adds lane*16 -> linear).
// DEEP PIPELINE (round-4 fix): tile t is staged ENTIRELY at P3 of group
// t-2 (8 gl_lds per thread). End-of-group wait = vmcnt(8): retains only
// tile g+2's stages, so tile g+1 (issued 5 phases earlier, ~775 cy in
// flight) is landed. Reads of buffer g&1 are confined to P1/P2 and
// retired at P2's lgkmcnt(0) before any wave reaches P3's stages into
// that same buffer (P2's closing barrier orders it).
// =====================================================================
#define MFMA16(a, b, c) __builtin_amdgcn_mfma_f32_16x16x32_bf16(a, b, c, 0, 0, 0)

__device__ __forceinline__ void BARRIER() {
    asm volatile("" ::: "memory");
    __builtin_amdgcn_s_barrier();
    asm volatile("" ::: "memory");
}
#define LGKM0() asm volatile("s_waitcnt lgkmcnt(0)" ::: "memory")

__device__ __forceinline__ bf16x8 lds_frag(const u16* base, int r, int c) {
    return *(const bf16x8*)((const char*)base + (r << 7) + ((c ^ (r & 7)) << 4));
}

// gbase includes tile-row origin and the per-lane swizzled chunk offset.
// lbase+wuoff is WAVE-UNIFORM; hardware writes lane l's 16B at +l*16.
__device__ __forceinline__ void stage_half(const u16* gbase, int K, u16* lbase,
                                           int kt, int h, int srow, int wuoff)
{
    const u16* gp = gbase + (size_t)(h * 128 + srow) * K + kt * 64;
    char* lp = (char*)lbase + h * 16384 + wuoff;          // wave-uniform
    gl_lds16(gp, (u16*)lp);                               // rows h*128 + [0,64)
    gl_lds16(gp + (size_t)64 * K, (u16*)(lp + 8192));     // rows h*128 + [64,128)
}

__device__ __forceinline__ void stage_tile(const u16* Ag, const u16* Bg, int K,
                                           u16* Ab, u16* Bb, int kt,
                                           int srow, int wuoff)
{
    stage_half(Ag, K, Ab, kt, 0, srow, wuoff);
    stage_half(Ag, K, Ab, kt, 1, srow, wuoff);
    stage_half(Bg, K, Bb, kt, 0, srow, wuoff);
    stage_half(Bg, K, Bb, kt, 1, srow, wuoff);
}

template <bool IS_QKV>
__global__ __launch_bounds__(512, 2)
void gemm256(const u16* __restrict__ A, const u16* __restrict__ Bt,
             const float* __restrict__ bias, void* __restrict__ Cout,
             int M, int N, int K)
{
    __shared__ u16 As[2][16384];   // [buf][256 rows x 64 cols]
    __shared__ u16 Bs[2][16384];

    const int tid = threadIdx.x;
    const int w   = tid >> 6;
    const int l   = tid & 63;
    const int wr  = w >> 2;            // 0..1  (M half)
    const int wc  = w & 3;             // 0..3  (N quarter)
    const int fr  = l & 15;            // fragment row
    const int ck0 = l >> 4;            // k-chunk 0..3 (ks0); ks1 = ck0+4

    // ---- bijective XCD-aware block remap (m204) ----
    const int gx = gridDim.x;
    const int nwg = gx * gridDim.y;
    const int orig = blockIdx.y * gx + blockIdx.x;
    const int qq = nwg >> 3, rr = nwg & 7;
    const int xcd = orig & 7, idx = orig >> 3;
    const int wg = (xcd < rr) ? (xcd * (qq + 1) + idx)
                              : (rr * (qq + 1) + (xcd - rr) * qq + idx);
    const int bx = wg % gx, by = wg / gx;
    const int m0 = by * 256, n0 = bx * 256;

    // ---- staging coords: this lane sources row srow(+64), swizzled chunk ----
    const int srow   = w * 8 + (l >> 3);            // 0..63
    const int schunk = ((l & 7) ^ (l >> 3)) * 8;    // element offset of 16B chunk
    const int wuoff  = w * 1024;                    // bytes, wave-uniform LDS base

    const u16* Ag = A  + (size_t)m0 * K + schunk;
    const u16* Bg = Bt + (size_t)n0 * K + schunk;

    f32x4 acc[8][4] = {};
    const int NT = K >> 6;             // K-tiles of 64 (=12 here)

    // ---- prologue: tile0 + tile1 fully staged; wait tile0 only ----
    stage_tile(Ag, Bg, K, As[0], Bs[0], 0, srow, wuoff);
    stage_tile(Ag, Bg, K, As[1], Bs[1], 1, srow, wuoff);
    asm volatile("s_waitcnt vmcnt(8)" ::: "memory");   // tile0 landed; tile1 in flight
    BARRIER();

    for (int g = 0; g < NT; ++g) {
        const u16* Ab = As[g & 1];
        const u16* Bb = Bs[g & 1];
        u16* Acu = As[g & 1];
        u16* Bcu = Bs[g & 1];

        bf16x8 a0[8], a1[8], b0[4], b1[4];

        // ---------- P1: read ks0 (a0, b0[0..1]), MFMA ks0 x n0-1 ----------
        #pragma unroll
        for (int mi = 0; mi < 8; ++mi) a0[mi] = lds_frag(Ab, wr * 128 + mi * 16 + fr, ck0);
        b0[0] = lds_frag(Bb, wc * 64 + 0 * 16 + fr, ck0);
        b0[1] = lds_frag(Bb, wc * 64 + 1 * 16 + fr, ck0);
        BARRIER();
        LGKM0();
        __builtin_amdgcn_s_setprio(1);
        #pragma unroll
        for (int mi = 0; mi < 8; ++mi) {
            acc[mi][0] = MFMA16(a0[mi], b0[0], acc[mi][0]);
            acc[mi][1] = MFMA16(a0[mi], b0[1], acc[mi][1]);
        }
        __builtin_amdgcn_s_setprio(0);
        BARRIER();

        // ---------- P2: read b0[2..3] + ks1 (a1, b1), MFMA ks0 x n2-3 ----------
        b0[2] = lds_frag(Bb, wc * 64 + 2 * 16 + fr, ck0);
        b0[3] = lds_frag(Bb, wc * 64 + 3 * 16 + fr, ck0);
        #pragma unroll
        for (int mi = 0; mi < 8; ++mi) a1[mi] = lds_frag(Ab, wr * 128 + mi * 16 + fr, ck0 + 4);
        #pragma unroll
        for (int ni = 0; ni < 4; ++ni) b1[ni] = lds_frag(Bb, wc * 64 + ni * 16 + fr, ck0 + 4);
        BARRIER();
        LGKM0();   // all reads of this buffer retired before P3's stages
        __builtin_amdgcn_s_setprio(1);
        #pragma unroll
        for (int mi = 0; mi < 8; ++mi) {
            acc[mi][2] = MFMA16(a0[mi], b0[2], acc[mi][2]);
            acc[mi][3] = MFMA16(a0[mi], b0[3], acc[mi][3]);
        }
        __builtin_amdgcn_s_setprio(0);
        BARRIER();

        // ---------- P3: stage ALL of tile g+2 into this buffer, MFMA ks1 x n0-1 ----------
        if (g + 2 < NT) stage_tile(Ag, Bg, K, Acu, Bcu, g + 2, srow, wuoff);
        BARRIER();
        __builtin_amdgcn_s_setprio(1);
        #pragma unroll
        for (int mi = 0; mi < 8; ++mi) {
            acc[mi][0] = MFMA16(a1[mi], b1[0], acc[mi][0]);
            acc[mi][1] = MFMA16(a1[mi], b1[1], acc[mi][1]);
        }
        __builtin_amdgcn_s_setprio(0);
        BARRIER();

        // ---------- P4: MFMA ks1 x n2-3, counted vmcnt (tile g+1 landed) ----------
        __builtin_amdgcn_s_setprio(1);
        #pragma unroll
        for (int mi = 0; mi < 8; ++mi) {
            acc[mi][2] = MFMA16(a1[mi], b1[2], acc[mi][2]);
            acc[mi][3] = MFMA16(a1[mi], b1[3], acc[mi][3]);
        }
        __builtin_amdgcn_s_setprio(0);
        if (g < NT - 2) { asm volatile("s_waitcnt vmcnt(8)" ::: "memory"); }
        else            { asm volatile("s_waitcnt vmcnt(0)" ::: "memory"); }
        BARRIER();
    }

    // ---- epilogue: C/D layout col = lane&15, row = (lane>>4)*4 + reg ----
    if (IS_QKV) {
        u16* C = (u16*)Cout;
        #pragma unroll
        for (int mi = 0; mi < 8; ++mi) {
            const int r0 = m0 + wr * 128 + mi * 16 + (l >> 4) * 4;
            #pragma unroll
            for (int ni = 0; ni < 4; ++ni) {
                const int col = n0 + wc * 64 + ni * 16 + fr;
                const float sc = (col < 768) ? 0.125f : 1.0f;   // q * HD^-0.5
                #pragma unroll
                for (int r = 0; r < 4; ++r)
                    C[(size_t)(r0 + r) * N + col] = f2bf(acc[mi][ni][r] * sc);
            }
        }
    } else {
        float* C = (float*)Cout;
        #pragma unroll
        for (int mi = 0; mi < 8; ++mi) {
            const int r0 = m0 + wr * 128 + mi * 16 + (l >> 4) * 4;
            #pragma unroll
            for (int ni = 0; ni < 4; ++ni) {
                const int col = n0 + wc * 64 + ni * 16 + fr;
                const float b = bias[col];
                #pragma unroll
                for (int r = 0; r < 4; ++r)
                    C[(size_t)(r0 + r) * N + col] = acc[mi][ni][r] + b;
            }
        }
    }
}

// =====================================================================
// sparse 3x3-window attention v3: one block per (batch, head).
// K,V for the 196 tokens staged in LDS (50 KB), chunk-XOR swizzled so
// the 8-query x 8-slot wave read pattern is bank-conflict-free.
// 256 threads = 4 waves x 8 queries x 8 lanes; 7 passes cover 196.
// =====================================================================
__device__ __forceinline__ void unpack8(uint4 d, float* f) {
    f[0] = __uint_as_float(d.x << 16); f[1] = __uint_as_float(d.x & 0xFFFF0000u);
    f[2] = __uint_as_float(d.y << 16); f[3] = __uint_as_float(d.y & 0xFFFF0000u);
    f[4] = __uint_as_float(d.z << 16); f[5] = __uint_as_float(d.z & 0xFFFF0000u);
    f[6] = __uint_as_float(d.w << 16); f[7] = __uint_as_float(d.w & 0xFFFF0000u);
}

__global__ __launch_bounds__(256)
void attn_lds(const u16* __restrict__ qkv, const float* __restrict__ rpb,
              u16* __restrict__ out)
{
    __shared__ u16 Ks[196 * 64];
    __shared__ u16 Vs[196 * 64];

    const int tid = threadIdx.x;
    const int bh  = blockIdx.x;          // b*12 + h
    const int b   = bh / 12;
    const int h   = bh - b * 12;
    const size_t base = (size_t)b * 196 * 2304 + h * 64;   // token 0 of this (b,h)

    // ---- stage K,V: 1568 16B-chunks each; swizzle chunk s of row t -> s ^ (t&7) ----
    for (int c = tid; c < 1568; c += 256) {
        const int t = c >> 3, s = c & 7;
        const u16* kg = qkv + base + (size_t)t * 2304 + 768 + s * 8;
        uint4 kd = *(const uint4*)kg;
        uint4 vd = *(const uint4*)(kg + 768);
        const int off = t * 64 + ((s * 8) ^ ((t & 7) << 3));   // u16 elements
        *(uint4*)&Ks[off] = kd;
        *(uint4*)&Vs[off] = vd;
    }

    // ---- per-block rpb: 9 scalars, uniform across the block ----
    float rpb9[9];
    #pragma unroll
    for (int a = 0; a < 9; ++a) {
        const int di = a / 3 - 1, dj = a % 3 - 1;
        rpb9[a] = rpb[((13 - di) * 27 + (13 - dj)) * 12 + h];
    }

    __syncthreads();

    const int w   = tid >> 6;            // wave 0..3
    const int sub = (tid >> 3) & 7;      // query within wave
    const int sl  = tid & 7;             // dims [sl*8, sl*8+8)

    for (int p = 0; p < 7; ++p) {
        const int t = p * 32 + w * 8 + sub;        // 0..223
        const bool qv = t < 196;
        const int tt = qv ? t : 195;
        const int i = tt / 14, j = tt % 14;

        float qf[8];
        unpack8(*(const uint4*)(qkv + base + (size_t)tt * 2304 + sl * 8), qf);

        // pass 1: scores (K from LDS)
        float s[9];
        int   t2a[9];
        #pragma unroll
        for (int a = 0; a < 9; ++a) {
            const int di = a / 3 - 1, dj = a % 3 - 1;
            const int i2 = i + di, j2 = j + dj;
            const bool valid = ((unsigned)i2 < 14u) && ((unsigned)j2 < 14u);
            const int t2 = valid ? (i2 * 14 + j2) : tt;
            t2a[a] = t2;
            float kf[8];
            unpack8(*(const uint4*)&Ks[t2 * 64 + ((sl * 8) ^ ((t2 & 7) << 3))], kf);
            float pp = qf[0] * kf[0];
            #pragma unroll
            for (int d = 1; d < 8; ++d) pp = fmaf(qf[d], kf[d], pp);
            pp += __shfl_xor(pp, 1);
            pp += __shfl_xor(pp, 2);
            pp += __shfl_xor(pp, 4);
            s[a] = valid ? (pp + rpb9[a]) : -1e30f;
        }
        float mx = s[0];
        #pragma unroll
        for (int a = 1; a < 9; ++a) mx = fmaxf(mx, s[a]);

        // pass 2: softmax + weighted V (V from LDS)
        float den = 0.f, o[8] = {};
        #pragma unroll
        for (int a = 0; a < 9; ++a) {
            float vf[8];
            const int t2 = t2a[a];
            unpack8(*(const uint4*)&Vs[t2 * 64 + ((sl * 8) ^ ((t2 & 7) << 3))], vf);
            const float pe = __expf(s[a] - mx);     // invalid -> exp(-huge) = 0
            den += pe;
            #pragma unroll
            for (int d = 0; d < 8; ++d) o[d] = fmaf(pe, vf[d], o[d]);
        }
        const float r = 1.0f / den;
        if (qv) {
            ushort4 o0, o1;
            o0.x = f2bf(o[0] * r); o0.y = f2bf(o[1] * r);
            o0.z = f2bf(o[2] * r); o0.w = f2bf(o[3] * r);
            o1.x = f2bf(o[4] * r); o1.y = f2bf(o[5] * r);
            o1.z = f2bf(o[6] * r); o1.w = f2bf(o[7] * r);
            u16* op = out + (size_t)(b * 196 + t) * 768 + h * 64 + sl * 8;
            *(ushort4*)op = o0;
            *(ushort4*)(op + 4) = o1;
        }
    }
}

// ---------------- launch ----------------
extern "C" void kernel_launch(void* const* d_in, const int* in_sizes, int n_in,
                              void* d_out, int out_size, void* d_ws, size_t ws_size,
                              hipStream_t stream)
{
    const float* x      = (const float*)d_in[0];   // [256,196,768]
    const float* w_qkv  = (const float*)d_in[1];   // [2304,768]
    const float* rpb    = (const float*)d_in[2];   // [729,12]
    const float* proj_w = (const float*)d_in[3];   // [768,768]
    const float* proj_b = (const float*)d_in[4];   // [768]
    // d_in[5] mask, d_in[6] rel_idx: handled analytically
    float* out = (float*)d_out;                    // [256,196,768]

    char* ws = (char*)d_ws;
    u16* x_bf    = (u16*)(ws);                    // 50176*768*2  = 77,070,336 B
    u16* wqkv_bf = (u16*)(ws + 77070336ULL);      // 2304*768*2   =  3,538,944 B
    u16* pw_bf   = (u16*)(ws + 80609280ULL);      // 768*768*2    =  1,179,648 B
    u16* qkv_bf  = (u16*)(ws + 81788928ULL);      // 50176*2304*2 = 231,211,008 B
    u16* attn_bf = (u16*)(ws + 312999936ULL);     // 50176*768*2  = 77,070,336 B
    // total 390,070,272 B

    cvt_bf16<<<37632, 256, 0, stream>>>((const float4*)x,      x_bf,    9633792);
    cvt_bf16<<<1728,  256, 0, stream>>>((const float4*)w_qkv,  wqkv_bf, 442368);
    cvt_bf16<<<576,   256, 0, stream>>>((const float4*)proj_w, pw_bf,   147456);

    // qkv = x @ w_qkv^T  (M=50176, N=2304, K=768), q cols scaled by 0.125
    gemm256<true><<<dim3(9, 196), 512, 0, stream>>>(
        x_bf, wqkv_bf, nullptr, qkv_bf, 50176, 2304, 768);

    // sparse local attention: one block per (batch, head)
    attn_lds<<<3072, 256, 0, stream>>>(qkv_bf, rpb, attn_bf);

    // out = attn @ proj_w^T + proj_b  (M=50176, N=768, K=768), fp32 out
    gemm256<false><<<dim3(3, 196), 512, 0, stream>>>(
        attn_bf, pw_bf, proj_b, out, 50176, 768, 768);
}

// Round 5
// 654.169 us; speedup vs baseline: 1.1563x; 1.0501x over previous
//
#include <hip/hip_runtime.h>
#include <cstdint>
#include <cstddef>

typedef unsigned short u16;
typedef __attribute__((ext_vector_type(8))) short bf16x8;
typedef __attribute__((ext_vector_type(4))) float f32x4;

__device__ __forceinline__ u16 f2bf(float f) {
    unsigned u = __float_as_uint(f);
    u += 0x7FFF + ((u >> 16) & 1);   // RNE
    return (u16)(u >> 16);
}

// ---------------- fused fp32 -> bf16 conversion (3 tensors, one launch) ----------------
__global__ __launch_bounds__(256)
void cvt3(const float4* __restrict__ a, u16* __restrict__ oa, int na4,
          const float4* __restrict__ b, u16* __restrict__ ob, int nb4,
          const float4* __restrict__ c, u16* __restrict__ oc, int nc4)
{
    int i = blockIdx.x * 256 + threadIdx.x;
    const float4* src; u16* dst; int idx;
    if (i < na4)                    { src = a; dst = oa; idx = i; }
    else if (i < na4 + nb4)         { src = b; dst = ob; idx = i - na4; }
    else if (i < na4 + nb4 + nc4)   { src = c; dst = oc; idx = i - na4 - nb4; }
    else return;
    float4 v = src[idx];
    ushort4 o;
    o.x = f2bf(v.x); o.y = f2bf(v.y); o.z = f2bf(v.z); o.w = f2bf(v.w);
    ((ushort4*)dst)[idx] = o;
}

__device__ __forceinline__ void gl_lds16(const u16* g, u16* l) {
    __builtin_amdgcn_global_load_lds(
        (const __attribute__((address_space(1))) void*)g,
        (__attribute__((address_space(3))) void*)l, 16, 0, 0);
}

// =====================================================================
// 256x256 8-phase bf16 GEMM:  C[M,N] = A[M,K] * Bt[N,K]^T
// BK=64, 8 waves (2Mx4N), per-wave 128x64 output (8x4 frags 16x16x32).
// LDS 128 KiB: 2 dbuf x (A 32KB + B 32KB). Chunk-XOR swizzle: row r's
// 16B chunk c stored at c ^ (r&7); applied via pre-swizzled GLOBAL src
// (global_load_lds dest is WAVE-UNIFORM base; HW adds lane*16 -> linear).
// Distributed staging (round-3 measured best: 225us / 34% MfmaUtil):
// P1:(g+1).Ah1  P2:(g+1).Bh1  P3:(g+2).Ah0  P4:(g+2).Bh0; end-of-group
// vmcnt(4) retains P3/P4's loads. Reads of tile g confined to P1/P2 and
// retired at P2's lgkmcnt(0) before P3 stages into the same buffer.
// At K=768 (12 groups) this lands ~34% MfmaUtil, consistent with the
// known K~1k ceiling of this structure (m248); deeper pipelining was
// measured WORSE (round 4: 240us), so this config is kept.
// =====================================================================
#define MFMA16(a, b, c) __builtin_amdgcn_mfma_f32_16x16x32_bf16(a, b, c, 0, 0, 0)

__device__ __forceinline__ void BARRIER() {
    asm volatile("" ::: "memory");
    __builtin_amdgcn_s_barrier();
    asm volatile("" ::: "memory");
}
#define LGKM0() asm volatile("s_waitcnt lgkmcnt(0)" ::: "memory")

__device__ __forceinline__ bf16x8 lds_frag(const u16* base, int r, int c) {
    return *(const bf16x8*)((const char*)base + (r << 7) + ((c ^ (r & 7)) << 4));
}

// gbase includes tile-row origin and the per-lane swizzled chunk offset.
// lbase+wuoff is WAVE-UNIFORM; hardware writes lane l's 16B at +l*16.
__device__ __forceinline__ void stage_half(const u16* gbase, int K, u16* lbase,
                                           int kt, int h, int srow, int wuoff)
{
    const u16* gp = gbase + (size_t)(h * 128 + srow) * K + kt * 64;
    char* lp = (char*)lbase + h * 16384 + wuoff;          // wave-uniform
    gl_lds16(gp, (u16*)lp);                               // rows h*128 + [0,64)
    gl_lds16(gp + (size_t)64 * K, (u16*)(lp + 8192));     // rows h*128 + [64,128)
}

template <bool IS_QKV>
__global__ __launch_bounds__(512, 2)
void gemm256(const u16* __restrict__ A, const u16* __restrict__ Bt,
             const float* __restrict__ bias, void* __restrict__ Cout,
             int M, int N, int K)
{
    __shared__ u16 As[2][16384];   // [buf][256 rows x 64 cols]
    __shared__ u16 Bs[2][16384];

    const int tid = threadIdx.x;
    const int w   = tid >> 6;
    const int l   = tid & 63;
    const int wr  = w >> 2;            // 0..1  (M half)
    const int wc  = w & 3;             // 0..3  (N quarter)
    const int fr  = l & 15;            // fragment row
    const int ck0 = l >> 4;            // k-chunk 0..3 (ks0); ks1 = ck0+4

    // ---- bijective XCD-aware block remap (m204) ----
    const int gx = gridDim.x;
    const int nwg = gx * gridDim.y;
    const int orig = blockIdx.y * gx + blockIdx.x;
    const int qq = nwg >> 3, rr = nwg & 7;
    const int xcd = orig & 7, idx = orig >> 3;
    const int wg = (xcd < rr) ? (xcd * (qq + 1) + idx)
                              : (rr * (qq + 1) + (xcd - rr) * qq + idx);
    const int bx = wg % gx, by = wg / gx;
    const int m0 = by * 256, n0 = bx * 256;

    // ---- staging coords: this lane sources row srow(+64), swizzled chunk ----
    const int srow   = w * 8 + (l >> 3);            // 0..63
    const int schunk = ((l & 7) ^ (l >> 3)) * 8;    // element offset of 16B chunk
    const int wuoff  = w * 1024;                    // bytes, wave-uniform LDS base

    const u16* Ag = A  + (size_t)m0 * K + schunk;
    const u16* Bg = Bt + (size_t)n0 * K + schunk;

    f32x4 acc[8][4] = {};
    const int NT = K >> 6;             // K-tiles of 64 (=12 here)

    // ---- prologue: tile0 fully, tile1 h0 ----
    stage_half(Ag, K, As[0], 0, 0, srow, wuoff);
    stage_half(Bg, K, Bs[0], 0, 0, srow, wuoff);
    stage_half(Ag, K, As[0], 0, 1, srow, wuoff);
    stage_half(Bg, K, Bs[0], 0, 1, srow, wuoff);
    stage_half(Ag, K, As[1], 1, 0, srow, wuoff);
    stage_half(Bg, K, Bs[1], 1, 0, srow, wuoff);
    asm volatile("s_waitcnt vmcnt(4)" ::: "memory");   // tile0 landed; tile1.h0 in flight
    BARRIER();

    for (int g = 0; g < NT; ++g) {
        const u16* Ab = As[g & 1];
        const u16* Bb = Bs[g & 1];
        u16* Anx = As[(g + 1) & 1];
        u16* Bnx = Bs[(g + 1) & 1];
        u16* Acu = As[g & 1];
        u16* Bcu = Bs[g & 1];

        bf16x8 a0[8], a1[8], b0[4], b1[4];

        // ---------- P1: read ks0 (a0, b0[0..1]), stage (g+1).Ah1, MFMA ks0 x n0-1 ----------
        #pragma unroll
        for (int mi = 0; mi < 8; ++mi) a0[mi] = lds_frag(Ab, wr * 128 + mi * 16 + fr, ck0);
        b0[0] = lds_frag(Bb, wc * 64 + 0 * 16 + fr, ck0);
        b0[1] = lds_frag(Bb, wc * 64 + 1 * 16 + fr, ck0);
        if (g + 1 < NT) stage_half(Ag, K, Anx, g + 1, 1, srow, wuoff);
        BARRIER();
        LGKM0();
        __builtin_amdgcn_s_setprio(1);
        #pragma unroll
        for (int mi = 0; mi < 8; ++mi) {
            acc[mi][0] = MFMA16(a0[mi], b0[0], acc[mi][0]);
            acc[mi][1] = MFMA16(a0[mi], b0[1], acc[mi][1]);
        }
        __builtin_amdgcn_s_setprio(0);
        BARRIER();

        // ---------- P2: read b0[2..3] + ks1 (a1, b1), stage (g+1).Bh1, MFMA ks0 x n2-3 ----------
        b0[2] = lds_frag(Bb, wc * 64 + 2 * 16 + fr, ck0);
        b0[3] = lds_frag(Bb, wc * 64 + 3 * 16 + fr, ck0);
        #pragma unroll
        for (int mi = 0; mi < 8; ++mi) a1[mi] = lds_frag(Ab, wr * 128 + mi * 16 + fr, ck0 + 4);
        #pragma unroll
        for (int ni = 0; ni < 4; ++ni) b1[ni] = lds_frag(Bb, wc * 64 + ni * 16 + fr, ck0 + 4);
        if (g + 1 < NT) stage_half(Bg, K, Bnx, g + 1, 1, srow, wuoff);
        BARRIER();
        LGKM0();   // all reads of this buffer retired before P3's stages
        __builtin_amdgcn_s_setprio(1);
        #pragma unroll
        for (int mi = 0; mi < 8; ++mi) {
            acc[mi][2] = MFMA16(a0[mi], b0[2], acc[mi][2]);
            acc[mi][3] = MFMA16(a0[mi], b0[3], acc[mi][3]);
        }
        __builtin_amdgcn_s_setprio(0);
        BARRIER();

        // ---------- P3: stage (g+2).Ah0, MFMA ks1 x n0-1 ----------
        if (g + 2 < NT) stage_half(Ag, K, Acu, g + 2, 0, srow, wuoff);
        BARRIER();
        __builtin_amdgcn_s_setprio(1);
        #pragma unroll
        for (int mi = 0; mi < 8; ++mi) {
            acc[mi][0] = MFMA16(a1[mi], b1[0], acc[mi][0]);
            acc[mi][1] = MFMA16(a1[mi], b1[1], acc[mi][1]);
        }
        __builtin_amdgcn_s_setprio(0);
        BARRIER();

        // ---------- P4: stage (g+2).Bh0, MFMA ks1 x n2-3, counted vmcnt ----------
        if (g + 2 < NT) stage_half(Bg, K, Bcu, g + 2, 0, srow, wuoff);
        __builtin_amdgcn_s_setprio(1);
        #pragma unroll
        for (int mi = 0; mi < 8; ++mi) {
            acc[mi][2] = MFMA16(a1[mi], b1[2], acc[mi][2]);
            acc[mi][3] = MFMA16(a1[mi], b1[3], acc[mi][3]);
        }
        __builtin_amdgcn_s_setprio(0);
        if (g < NT - 2) { asm volatile("s_waitcnt vmcnt(4)" ::: "memory"); }
        else            { asm volatile("s_waitcnt vmcnt(0)" ::: "memory"); }
        BARRIER();
    }

    // ---- epilogue: C/D layout col = lane&15, row = (lane>>4)*4 + reg ----
    if (IS_QKV) {
        u16* C = (u16*)Cout;
        #pragma unroll
        for (int mi = 0; mi < 8; ++mi) {
            const int r0 = m0 + wr * 128 + mi * 16 + (l >> 4) * 4;
            #pragma unroll
            for (int ni = 0; ni < 4; ++ni) {
                const int col = n0 + wc * 64 + ni * 16 + fr;
                const float sc = (col < 768) ? 0.125f : 1.0f;   // q * HD^-0.5
                #pragma unroll
                for (int r = 0; r < 4; ++r)
                    C[(size_t)(r0 + r) * N + col] = f2bf(acc[mi][ni][r] * sc);
            }
        }
    } else {
        float* C = (float*)Cout;
        #pragma unroll
        for (int mi = 0; mi < 8; ++mi) {
            const int r0 = m0 + wr * 128 + mi * 16 + (l >> 4) * 4;
            #pragma unroll
            for (int ni = 0; ni < 4; ++ni) {
                const int col = n0 + wc * 64 + ni * 16 + fr;
                const float b = bias[col];
                #pragma unroll
                for (int r = 0; r < 4; ++r)
                    C[(size_t)(r0 + r) * N + col] = acc[mi][ni][r] + b;
            }
        }
    }
}

// =====================================================================
// sparse 3x3-window attention v4: one block per (batch, head).
// ONLY K staged in LDS (25 KB -> ~6 blocks/CU, 24 waves/CU of TLP).
// V (25 KB/panel) is read from global: L1/L2-resident after first use.
// 256 threads = 4 waves x 8 queries x 8 lanes; 7 passes cover 196.
// =====================================================================
__device__ __forceinline__ void unpack8(uint4 d, float* f) {
    f[0] = __uint_as_float(d.x << 16); f[1] = __uint_as_float(d.x & 0xFFFF0000u);
    f[2] = __uint_as_float(d.y << 16); f[3] = __uint_as_float(d.y & 0xFFFF0000u);
    f[4] = __uint_as_float(d.z << 16); f[5] = __uint_as_float(d.z & 0xFFFF0000u);
    f[6] = __uint_as_float(d.w << 16); f[7] = __uint_as_float(d.w & 0xFFFF0000u);
}

__global__ __launch_bounds__(256)
void attn_k_lds(const u16* __restrict__ qkv, const float* __restrict__ rpb,
                u16* __restrict__ out)
{
    __shared__ u16 Ks[196 * 64];         // 25,088 B

    const int tid = threadIdx.x;
    const int bh  = blockIdx.x;          // b*12 + h
    const int b   = bh / 12;
    const int h   = bh - b * 12;
    const size_t base = (size_t)b * 196 * 2304 + h * 64;   // token 0 of this (b,h)

    // ---- stage K: 1568 16B-chunks; swizzle chunk s of row t -> s ^ (t&7) ----
    for (int c = tid; c < 1568; c += 256) {
        const int t = c >> 3, s = c & 7;
        uint4 kd = *(const uint4*)(qkv + base + (size_t)t * 2304 + 768 + s * 8);
        *(uint4*)&Ks[t * 64 + ((s * 8) ^ ((t & 7) << 3))] = kd;
    }

    // ---- per-block rpb: 9 scalars, uniform across the block ----
    float rpb9[9];
    #pragma unroll
    for (int a = 0; a < 9; ++a) {
        const int di = a / 3 - 1, dj = a % 3 - 1;
        rpb9[a] = rpb[((13 - di) * 27 + (13 - dj)) * 12 + h];
    }

    __syncthreads();

    const int w   = tid >> 6;            // wave 0..3
    const int sub = (tid >> 3) & 7;      // query within wave
    const int sl  = tid & 7;             // dims [sl*8, sl*8+8)

    for (int p = 0; p < 7; ++p) {
        const int t = p * 32 + w * 8 + sub;        // 0..223
        const bool qv = t < 196;
        const int tt = qv ? t : 195;
        const int i = tt / 14, j = tt % 14;

        float qf[8];
        unpack8(*(const uint4*)(qkv + base + (size_t)tt * 2304 + sl * 8), qf);

        // pass 1: scores (K from LDS)
        float s[9];
        int   t2a[9];
        #pragma unroll
        for (int a = 0; a < 9; ++a) {
            const int di = a / 3 - 1, dj = a % 3 - 1;
            const int i2 = i + di, j2 = j + dj;
            const bool valid = ((unsigned)i2 < 14u) && ((unsigned)j2 < 14u);
            const int t2 = valid ? (i2 * 14 + j2) : tt;
            t2a[a] = t2;
            float kf[8];
            unpack8(*(const uint4*)&Ks[t2 * 64 + ((sl * 8) ^ ((t2 & 7) << 3))], kf);
            float pp = qf[0] * kf[0];
            #pragma unroll
            for (int d = 1; d < 8; ++d) pp = fmaf(qf[d], kf[d], pp);
            pp += __shfl_xor(pp, 1);
            pp += __shfl_xor(pp, 2);
            pp += __shfl_xor(pp, 4);
            s[a] = valid ? (pp + rpb9[a]) : -1e30f;
        }
        float mx = s[0];
        #pragma unroll
        for (int a = 1; a < 9; ++a) mx = fmaxf(mx, s[a]);

        // pass 2: softmax + weighted V (V from global; panel is L1/L2-hot)
        float den = 0.f, o[8] = {};
        #pragma unroll
        for (int a = 0; a < 9; ++a) {
            float vf[8];
            unpack8(*(const uint4*)(qkv + base + (size_t)t2a[a] * 2304 + 1536 + sl * 8), vf);
            const float pe = __expf(s[a] - mx);     // invalid -> exp(-huge) = 0
            den += pe;
            #pragma unroll
            for (int d = 0; d < 8; ++d) o[d] = fmaf(pe, vf[d], o[d]);
        }
        const float r = 1.0f / den;
        if (qv) {
            ushort4 o0, o1;
            o0.x = f2bf(o[0] * r); o0.y = f2bf(o[1] * r);
            o0.z = f2bf(o[2] * r); o0.w = f2bf(o[3] * r);
            o1.x = f2bf(o[4] * r); o1.y = f2bf(o[5] * r);
            o1.z = f2bf(o[6] * r); o1.w = f2bf(o[7] * r);
            u16* op = out + (size_t)(b * 196 + t) * 768 + h * 64 + sl * 8;
            *(ushort4*)op = o0;
            *(ushort4*)(op + 4) = o1;
        }
    }
}

// ---------------- launch ----------------
extern "C" void kernel_launch(void* const* d_in, const int* in_sizes, int n_in,
                              void* d_out, int out_size, void* d_ws, size_t ws_size,
                              hipStream_t stream)
{
    const float* x      = (const float*)d_in[0];   // [256,196,768]
    const float* w_qkv  = (const float*)d_in[1];   // [2304,768]
    const float* rpb    = (const float*)d_in[2];   // [729,12]
    const float* proj_w = (const float*)d_in[3];   // [768,768]
    const float* proj_b = (const float*)d_in[4];   // [768]
    // d_in[5] mask, d_in[6] rel_idx: handled analytically
    float* out = (float*)d_out;                    // [256,196,768]

    char* ws = (char*)d_ws;
    u16* x_bf    = (u16*)(ws);                    // 50176*768*2  = 77,070,336 B
    u16* wqkv_bf = (u16*)(ws + 77070336ULL);      // 2304*768*2   =  3,538,944 B
    u16* pw_bf   = (u16*)(ws + 80609280ULL);      // 768*768*2    =  1,179,648 B
    u16* qkv_bf  = (u16*)(ws + 81788928ULL);      // 50176*2304*2 = 231,211,008 B
    u16* attn_bf = (u16*)(ws + 312999936ULL);     // 50176*768*2  = 77,070,336 B
    // total 390,070,272 B

    // fused conversion: x (9,633,792 f4) + w_qkv (442,368 f4) + proj_w (147,456 f4)
    cvt3<<<39936, 256, 0, stream>>>((const float4*)x,      x_bf,    9633792,
                                    (const float4*)w_qkv,  wqkv_bf, 442368,
                                    (const float4*)proj_w, pw_bf,   147456);

    // qkv = x @ w_qkv^T  (M=50176, N=2304, K=768), q cols scaled by 0.125
    gemm256<true><<<dim3(9, 196), 512, 0, stream>>>(
        x_bf, wqkv_bf, nullptr, qkv_bf, 50176, 2304, 768);

    // sparse local attention: one block per (batch, head)
    attn_k_lds<<<3072, 256, 0, stream>>>(qkv_bf, rpb, attn_bf);

    // out = attn @ proj_w^T + proj_b  (M=50176, N=768, K=768), fp32 out
    gemm256<false><<<dim3(3, 196), 512, 0, stream>>>(
        attn_bf, pw_bf, proj_b, out, 50176, 768, 768);
}